// Round 6
// baseline (233.463 us; speedup 1.0000x reference)
//
#include <hip/hip_runtime.h>
#include <stdint.h>
#include <math.h>

#define BB 2
#define SS 2048
#define DM 1024
#define NH 16
#define HD 64
#define MTOT (BB*SS)

typedef __bf16 bf16x8 __attribute__((ext_vector_type(8)));
typedef float  f32x4  __attribute__((ext_vector_type(4)));
typedef float  f32x16 __attribute__((ext_vector_type(16)));
typedef uint32_t u32x4 __attribute__((ext_vector_type(4)));

__device__ __forceinline__ unsigned short f2bf(float f) {
  __bf16 h = (__bf16)f;                 // RNE; compiler packs to v_cvt_pk_bf16_f32
  return __builtin_bit_cast(unsigned short, h);
}

__device__ __forceinline__ bf16x8 ldsv8(const unsigned short* p) {
  return __builtin_bit_cast(bf16x8, *(const u32x4*)p);
}

__device__ __forceinline__ void gl16(const void* g, void* l) {
  __builtin_amdgcn_global_load_lds(
      (const __attribute__((address_space(1))) uint32_t*)g,
      (__attribute__((address_space(3))) uint32_t*)l, 16, 0, 0);
}

#define MFMA16(a,b,c) __builtin_amdgcn_mfma_f32_16x16x32_bf16((a),(b),(c),0,0,0)
#define MFMA32(a,b,c) __builtin_amdgcn_mfma_f32_32x32x16_bf16((a),(b),(c),0,0,0)

// gate/softmax constants
#define C_NEG5L2E  (-7.213475204444817f)   // -5*log2(e)
#define C_L2E      (1.4426950408889634f)   // log2(e)
#define C_18L2E    (25.968510736001341f)   // 18*log2(e)

// ---------------- prep: fp32 -> bf16 convert of q/k/v activations ----------------
__global__ __launch_bounds__(256) void cvt_bf16(
    const float* __restrict__ a, const float* __restrict__ b, const float* __restrict__ c,
    unsigned short* __restrict__ ao, unsigned short* __restrict__ bo, unsigned short* __restrict__ co)
{
  const int i8 = (blockIdx.x * 256 + threadIdx.x) * 8;
  {
    const float4 f0 = *(const float4*)(a + i8);
    const float4 f1 = *(const float4*)(a + i8 + 4);
    union { unsigned short us[8]; u32x4 v; } t;
    t.us[0]=f2bf(f0.x); t.us[1]=f2bf(f0.y); t.us[2]=f2bf(f0.z); t.us[3]=f2bf(f0.w);
    t.us[4]=f2bf(f1.x); t.us[5]=f2bf(f1.y); t.us[6]=f2bf(f1.z); t.us[7]=f2bf(f1.w);
    *(u32x4*)(ao + i8) = t.v;
  }
  {
    const float4 f0 = *(const float4*)(b + i8);
    const float4 f1 = *(const float4*)(b + i8 + 4);
    union { unsigned short us[8]; u32x4 v; } t;
    t.us[0]=f2bf(f0.x); t.us[1]=f2bf(f0.y); t.us[2]=f2bf(f0.z); t.us[3]=f2bf(f0.w);
    t.us[4]=f2bf(f1.x); t.us[5]=f2bf(f1.y); t.us[6]=f2bf(f1.z); t.us[7]=f2bf(f1.w);
    *(u32x4*)(bo + i8) = t.v;
  }
  {
    const float4 f0 = *(const float4*)(c + i8);
    const float4 f1 = *(const float4*)(c + i8 + 4);
    union { unsigned short us[8]; u32x4 v; } t;
    t.us[0]=f2bf(f0.x); t.us[1]=f2bf(f0.y); t.us[2]=f2bf(f0.z); t.us[3]=f2bf(f0.w);
    t.us[4]=f2bf(f1.x); t.us[5]=f2bf(f1.y); t.us[6]=f2bf(f1.z); t.us[7]=f2bf(f1.w);
    *(u32x4*)(co + i8) = t.v;
  }
}

// ---------------- prep: quaternion weight build + bf16 conversion ----------------
__global__ __launch_bounds__(256) void prep_w(
    const float* __restrict__ wqr, const float* __restrict__ wqi,
    const float* __restrict__ wqj, const float* __restrict__ wqk,
    const float* __restrict__ wkr, const float* __restrict__ wki,
    const float* __restrict__ wkj, const float* __restrict__ wkk,
    const float* __restrict__ wv,  const float* __restrict__ wo,
    unsigned short* __restrict__ Wq, unsigned short* __restrict__ Wk,
    unsigned short* __restrict__ Wv, unsigned short* __restrict__ Wo)
{
  const int idx = blockIdx.x * 256 + threadIdx.x;
  const int o = idx >> 10, i = idx & 1023;
  const int br = o >> 8, bc = i >> 8;
  const int ro = o & 255, ci = i & 255;
  const int comp[4][4] = {{0,1,2,3},{1,0,3,2},{2,3,0,1},{3,2,1,0}};
  const float sgn[4][4] = {{1.f,-1.f,-1.f,-1.f},{1.f,1.f,-1.f,1.f},{1.f,1.f,1.f,-1.f},{1.f,-1.f,1.f,1.f}};
  const float* pq[4] = {wqr, wqi, wqj, wqk};
  const float* pk[4] = {wkr, wki, wkj, wkk};
  const int c_ = comp[br][bc];
  const float s_ = sgn[br][bc];
  const int pidx = ro * 256 + ci;
  Wq[idx] = f2bf(s_ * pq[c_][pidx]);
  Wk[idx] = f2bf(s_ * pk[c_][pidx]);
  Wv[idx] = f2bf(wv[idx]);
  Wo[idx] = f2bf(wo[idx]);
}

// ---------------- prep: per-(b,n) threshold -> kth (exp2 offset), klm (mask bound), fbits ----------------
__global__ __launch_bounds__(256) void prep_thr(
    const float* __restrict__ density, const float* __restrict__ dm1w,
    const float* __restrict__ dm1b, const float* __restrict__ dm2w,
    const float* __restrict__ dm2b, const float* __restrict__ thr_s,
    const int* __restrict__ mask, float* __restrict__ kth,
    float* __restrict__ klm, unsigned int* __restrict__ fbits)
{
  const int i = blockIdx.x * 256 + threadIdx.x;  // over B*S = 4096
  if (i >= BB * SS) return;
  const float x0 = density[i*3+0], x1 = density[i*3+1], x2 = density[i*3+2];
  const float base = log1pf(expf(thr_s[0]));     // softplus
  float acc = dm2b[0];
  #pragma unroll
  for (int j = 0; j < 16; ++j) {
    const float hj = dm1w[j*3+0]*x0 + dm1w[j*3+1]*x1 + dm1w[j*3+2]*x2 + dm1b[j];
    const float ge = 0.5f * hj * (1.0f + erff(hj * 0.70710678118654752f)); // exact gelu
    acc += dm2w[j] * ge;
  }
  const float thr = base + 0.1f * acc;
  const int mk = mask[i];
  kth[i] = thr * (-C_NEG5L2E);           // +5*log2e*thr
  klm[i] = mk ? 1e30f : -30.0f;
  const unsigned long long any = __ballot(mk == 0);
  if ((threadIdx.x & 63) == 0 && any)
    atomicOr(&fbits[i >> 11], 1u << ((i >> 6) & 31));  // per-64-key-tile mask flag
}

// ---------------- GEMM: C(M=4096,N=1024) = A(M,K=1024) @ W(N,K)^T + bias ----------------
struct GemmArgs {
  const unsigned short* A[3];
  const unsigned short* W[3];
  const float* bias[3];
  void* out[3];
  float scale[3];
  int omode[3];
};

template<int DB>
__global__ __launch_bounds__(256) void gemm_bt(GemmArgs args)
{
  __shared__ __align__(16) unsigned short lA[DB + 1][128*64];
  __shared__ __align__(16) unsigned short lB[DB + 1][128*64];
  const int z = blockIdx.y;
  const int tid = threadIdx.x;
  const int wid = tid >> 6, lane = tid & 63;
  const int l15 = lane & 15, l4 = lane >> 4;
  const int bm = blockIdx.x & 31, bn = blockIdx.x >> 5;   // XCD-aware decode
  const int row0 = bm * 128, col0 = bn * 128;
  const int wm = (wid >> 1) * 64, wn = (wid & 1) * 64;

  const unsigned short* gA[4];
  const unsigned short* gB[4];
  #pragma unroll
  for (int i = 0; i < 4; ++i) {
    const int c = (wid * 4 + i) * 64 + lane;
    const int r = c >> 3, jx = c & 7, j = jx ^ (r & 7);
    gA[i] = args.A[z] + (row0 + r) * 1024 + j * 8;
    gB[i] = args.W[z] + (col0 + r) * 1024 + j * 8;
  }

  f32x4 acc[4][4];
  #pragma unroll
  for (int i = 0; i < 4; ++i)
    #pragma unroll
    for (int j = 0; j < 4; ++j) acc[i][j] = (f32x4){0.f,0.f,0.f,0.f};

  #pragma unroll
  for (int i = 0; i < 4; ++i) {
    gl16(gA[i], &lA[0][(wid * 4 + i) * 512]);
    gl16(gB[i], &lB[0][(wid * 4 + i) * 512]);
  }
  if (DB) __syncthreads();

  for (int kt = 0; kt < 16; ++kt) {
    const int cb = DB ? (kt & 1) : 0;
    if (DB) {
      if (kt < 15) {
        const int nb = cb ^ 1, k0 = (kt + 1) * 64;
        #pragma unroll
        for (int i = 0; i < 4; ++i) {
          gl16(gA[i] + k0, &lA[nb][(wid * 4 + i) * 512]);
          gl16(gB[i] + k0, &lB[nb][(wid * 4 + i) * 512]);
        }
      }
    } else {
      if (kt > 0) {
        const int k0 = kt * 64;
        #pragma unroll
        for (int i = 0; i < 4; ++i) {
          gl16(gA[i] + k0, &lA[0][(wid * 4 + i) * 512]);
          gl16(gB[i] + k0, &lB[0][(wid * 4 + i) * 512]);
        }
      }
      __syncthreads();
    }
    #pragma unroll
    for (int kk = 0; kk < 2; ++kk) {
      const int kl = kk * 32 + l4 * 8;
      bf16x8 af[4], bfb[4];
      #pragma unroll
      for (int mi = 0; mi < 4; ++mi) {
        const int r = wm + mi * 16 + l15;
        af[mi] = ldsv8(&lA[cb][r * 64 + (kl ^ ((r & 7) << 3))]);
      }
      #pragma unroll
      for (int nj = 0; nj < 4; ++nj) {
        const int r = wn + nj * 16 + l15;
        bfb[nj] = ldsv8(&lB[cb][r * 64 + (kl ^ ((r & 7) << 3))]);
      }
      #pragma unroll
      for (int mi = 0; mi < 4; ++mi)
        #pragma unroll
        for (int nj = 0; nj < 4; ++nj)
          acc[mi][nj] = MFMA16(af[mi], bfb[nj], acc[mi][nj]);
    }
    __syncthreads();
  }

  const int om = args.omode[z];
  const float sc = args.scale[z];
  void* Cptr = args.out[z];
  #pragma unroll
  for (int nj = 0; nj < 4; ++nj) {
    const int c = col0 + wn + nj * 16 + l15;
    const float bv_ = args.bias[z][c];
    #pragma unroll
    for (int mi = 0; mi < 4; ++mi) {
      const int rb = row0 + wm + mi * 16 + l4 * 4;
      #pragma unroll
      for (int e = 0; e < 4; ++e) {
        const float val = (acc[mi][nj][e] + bv_) * sc;
        const int r = rb + e;
        if (om == 0) {
          ((unsigned short*)Cptr)[r * 1024 + c] = f2bf(val);
        } else if (om == 2) {
          ((float*)Cptr)[r * 1024 + c] = val;
        } else {
          const int h = c >> 6, d = c & 63, b = r >> 11, s = r & 2047;
          ((unsigned short*)Cptr)[((h * BB + b) * HD + d) * SS + s] = f2bf(val);
        }
      }
    }
  }
}

// ---------------- flash attention: 32x32 MFMA, swapped QK^T, in-register P ----------------
// 512 threads = 8 waves = 4 row-groups(32 rows) x 2 key-parities(32 keys of each 64-key pair).
// S^T = mfma(A=K, B=Q): lane holds one q-row (lane&31), 16 reg-mapped keys.
// P assembled in-register (cvt_pk + shfl_xor 32) into PV A-fragments. Fixed-max softmax.
__global__ __launch_bounds__(512, 4) void attn_kernel(
    const unsigned short* __restrict__ qg, const unsigned short* __restrict__ kg,
    const unsigned short* __restrict__ vT, const float* __restrict__ kth_g,
    const float* __restrict__ klm_g, const unsigned int* __restrict__ fbits,
    unsigned short* __restrict__ outg)
{
  // buffers: 2 x { K 8KB (2 parity x 16row x 256B), V 8KB, kth 256B, klm 256B } = 33792 B
  // merge phase reuses: lsums 2KB @0, dinv 512B @2048, O-dump 32KB @4096  -> 36864 B total
  __shared__ __align__(16) unsigned char smem[36864];
  const int tid = threadIdx.x;
  const int lane = tid & 63, wid = tid >> 6;
  const int l31 = lane & 31, l5 = lane >> 5;
  const int rg = wid >> 1, par = wid & 1;
  const int hb = blockIdx.x & 31, qc = blockIdx.x >> 5;   // XCD: same (h,b) -> same XCD
  const int h = hb >> 1, b = hb & 1;
  const int qr0 = qc * 128 + rg * 32;

  const unsigned short* kbase = kg + (size_t)(b * SS) * DM + h * HD;
  const unsigned short* vbase = vT + (size_t)((h * BB + b) * HD) * SS;
  const float* kthb = kth_g + b * SS;
  const float* klmb = klm_g + b * SS;
  const unsigned int fb = fbits[b];

  // staging addressing (per 64-key pair): K: key sk, hd-chunk sj. V: d sk, key-chunk sj.
  const int sk = tid >> 3, sj = tid & 7;
  const int kp = sk >> 5, kkl = sk & 31;
  const int kdst = kp*4096 + (kkl>>1)*256 + (((((kkl&1)<<3)|sj)) ^ ((kkl>>1)&15))*16;
  const int vp = sj >> 2, vjj = sj & 3;
  const int vdst = 8192 + vp*4096 + (sk>>2)*256 + (((((sk&3)<<2)|vjj)) ^ ((sk>>2)&15))*16;
  const unsigned short* kgsrc = kbase + sk * DM + sj * 8;
  const unsigned short* vgsrc = vbase + (size_t)sk * SS + sj * 8;

  // Q B-fragments (col=qrow=lane&31, k=hd ks*16 + l5*8); Q pre-scaled by 0.25
  bf16x8 bq[4];
  {
    const unsigned short* qs = qg + (size_t)(b * SS + qr0 + l31) * DM + h * HD + l5 * 8;
    #pragma unroll
    for (int ks = 0; ks < 4; ++ks)
      bq[ks] = __builtin_bit_cast(bf16x8, *(const u32x4*)(qs + ks * 16));
  }
  const float limq = klmb[qr0 + l31];   // per-lane q-row mask bound

  f32x16 O0 = {}, O1 = {};
  float lsum = 0.f;

  // prologue: stage pair 0
  u32x4 kr = *(const u32x4*)kgsrc;
  u32x4 vr = *(const u32x4*)vgsrc;
  f32x4 tk, tl;
  if (tid < 16)      tk = *(const f32x4*)(kthb + tid * 4);
  else if (tid < 32) tl = *(const f32x4*)(klmb + (tid - 16) * 4);
  *(u32x4*)(smem + kdst) = kr;
  *(u32x4*)(smem + vdst) = vr;
  if (tid < 16)      *(f32x4*)(smem + 16384 + tid * 16) = tk;
  else if (tid < 32) *(f32x4*)(smem + 16640 + (tid - 16) * 16) = tl;
  __syncthreads();

  for (int pr = 0; pr < 32; ++pr) {
    unsigned char* cb = smem + (pr & 1) * 16896;
    const int n0 = pr * 64;

    // prefetch next pair into regs
    if (pr < 31) {
      kr = *(const u32x4*)(kgsrc + (size_t)(n0 + 64) * DM);
      vr = *(const u32x4*)(vgsrc + n0 + 64);
      if (tid < 16)      tk = *(const f32x4*)(kthb + n0 + 64 + tid * 4);
      else if (tid < 32) tl = *(const f32x4*)(klmb + n0 + 64 + (tid - 16) * 4);
    }

    // per-key kth (broadcast reads: 2 addrs per wave)
    f32x4 kth4[4];
    #pragma unroll
    for (int g2 = 0; g2 < 4; ++g2)
      kth4[g2] = *(const f32x4*)(cb + 16384 + par*128 + g2*32 + l5*16);

    // S^T = K @ Q : lane = qrow (col), reg-mapped keys (rows)
    f32x16 S = {};
    {
      const unsigned char* Kb = cb + par * 4096;
      const int krow = l31 >> 1;
      __builtin_amdgcn_s_setprio(1);
      #pragma unroll
      for (int ks = 0; ks < 4; ++ks) {
        const int slot = ((((l31 & 1) << 3) | (ks*2 + l5)) ^ (krow & 15));
        bf16x8 ka = __builtin_bit_cast(bf16x8, *(const u32x4*)(Kb + krow*256 + slot*16));
        S = MFMA32(ka, bq[ks], S);
      }
      __builtin_amdgcn_s_setprio(0);
    }

    // spike gate + mask + fixed-max softmax numerator; key(r) = (r&3)+8*(r>>2)+4*l5
    float p[16];
    if (!((fb >> pr) & 1)) {
      #pragma unroll
      for (int r = 0; r < 16; ++r) {
        float s = fminf(fmaxf(S[r], -6.f), 6.f);
        const float t = __builtin_amdgcn_exp2f(fmaf(s, C_NEG5L2E, kth4[r>>2][r&3]));
        const float g = __builtin_amdgcn_rcpf(1.f + t);
        float md = fmaf(s + s, g, s);
        md = fminf(md, limq);
        const float pv = __builtin_amdgcn_exp2f(fmaf(md, C_L2E, -C_18L2E));
        p[r] = pv;
        lsum += pv;
      }
    } else {
      f32x4 klm4[4];
      #pragma unroll
      for (int g2 = 0; g2 < 4; ++g2)
        klm4[g2] = *(const f32x4*)(cb + 16640 + par*128 + g2*32 + l5*16);
      #pragma unroll
      for (int r = 0; r < 16; ++r) {
        float s = fminf(fmaxf(S[r], -6.f), 6.f);
        const float t = __builtin_amdgcn_exp2f(fmaf(s, C_NEG5L2E, kth4[r>>2][r&3]));
        const float g = __builtin_amdgcn_rcpf(1.f + t);
        float md = fmaf(s + s, g, s);
        md = fminf(md, fminf(klm4[r>>2][r&3], limq));
        const float pv = __builtin_amdgcn_exp2f(fmaf(md, C_L2E, -C_18L2E));
        p[r] = pv;
        lsum += pv;
      }
    }

    // assemble PV A-fragments in-register: c[i] = bf16 pair (keys 2i,2i+1 of lane's set)
    unsigned int c[8], cp[8];
    #pragma unroll
    for (int i = 0; i < 8; ++i) {
      union { unsigned short us[2]; unsigned int u; } t2;
      t2.us[0] = f2bf(p[2*i]); t2.us[1] = f2bf(p[2*i+1]);
      c[i] = t2.u;
    }
    #pragma unroll
    for (int i = 0; i < 8; ++i) cp[i] = (unsigned int)__shfl_xor((int)c[i], 32);
    bf16x8 pa0, pa1;
    {
      union { unsigned int u[4]; bf16x8 v; } fa;
      fa.u[0] = l5 ? cp[2] : c[0];
      fa.u[1] = l5 ? cp[3] : c[1];
      fa.u[2] = l5 ? c[2]  : cp[0];
      fa.u[3] = l5 ? c[3]  : cp[1];
      pa0 = fa.v;
      fa.u[0] = l5 ? cp[6] : c[4];
      fa.u[1] = l5 ? cp[7] : c[5];
      fa.u[2] = l5 ? c[6]  : cp[4];
      fa.u[3] = l5 ? c[7]  : cp[5];
      pa1 = fa.v;
    }

    // PV: O[dt] += P @ V  (B-frag: col=d=lane&31, k=keys ks2*16 + l5*8)
    {
      const unsigned char* Vb = cb + 8192 + par * 4096;
      __builtin_amdgcn_s_setprio(1);
      #pragma unroll
      for (int dt = 0; dt < 2; ++dt) {
        const int vrow = dt*8 + (l31 >> 2);
        #pragma unroll
        for (int ks2 = 0; ks2 < 2; ++ks2) {
          const int slot = ((((l31 & 3) << 2) | (ks2*2 + l5)) ^ (vrow & 15));
          bf16x8 bv = __builtin_bit_cast(bf16x8, *(const u32x4*)(Vb + vrow*256 + slot*16));
          if (dt == 0) O0 = MFMA32(ks2 ? pa1 : pa0, bv, O0);
          else         O1 = MFMA32(ks2 ? pa1 : pa0, bv, O1);
        }
      }
      __builtin_amdgcn_s_setprio(0);
    }

    // write staged next pair
    if (pr < 31) {
      unsigned char* nb = smem + ((pr + 1) & 1) * 16896;
      *(u32x4*)(nb + kdst) = kr;
      *(u32x4*)(nb + vdst) = vr;
      if (tid < 16)      *(f32x4*)(nb + 16384 + tid * 16) = tk;
      else if (tid < 32) *(f32x4*)(nb + 16640 + (tid - 16) * 16) = tl;
    }
    __syncthreads();
  }

  // ---- merge parity partials; normalize; store ----
  float* xf = (float*)smem;
  xf[(rg*2 + par)*64 + lane] = lsum;
  __syncthreads();
  float* dinv = (float*)(smem + 2048);
  if (par == 0 && lane < 32) {
    const float* ls0 = xf + rg * 128;
    const float den = ls0[lane] + ls0[32 + lane] + ls0[64 + lane] + ls0[96 + lane];
    dinv[rg*32 + lane] = __builtin_amdgcn_rcpf(den);
  }
  __syncthreads();
  float* od = (float*)(smem + 4096) + rg * 2048;
  if (par) {
    #pragma unroll
    for (int r = 0; r < 16; ++r) {
      od[r*64 + lane]        = O0[r];
      od[(16 + r)*64 + lane] = O1[r];
    }
  }
  __syncthreads();
  if (!par) {
    unsigned short* ob = outg + (size_t)(b * SS + qr0) * DM + h * HD;
    #pragma unroll
    for (int r = 0; r < 16; ++r) {
      const int row = (r & 3) + 8*(r >> 2) + 4*l5;
      const float di = dinv[rg*32 + row];
      const float v0 = O0[r] + od[r*64 + lane];
      const float v1 = O1[r] + od[(16 + r)*64 + lane];
      ob[(size_t)row * DM + l31]      = f2bf(v0 * di);
      ob[(size_t)row * DM + 32 + l31] = f2bf(v1 * di);
    }
  }
}

// ---------------- launcher ----------------
extern "C" void kernel_launch(void* const* d_in, const int* in_sizes, int n_in,
                              void* d_out, int out_size, void* d_ws, size_t ws_size,
                              hipStream_t stream)
{
  const float* query   = (const float*)d_in[0];
  const float* key_in  = (const float*)d_in[1];
  const float* value   = (const float*)d_in[2];
  const int*   mask    = (const int*)d_in[3];
  const float* density = (const float*)d_in[4];
  const float* wq_r = (const float*)d_in[5];
  const float* wq_i = (const float*)d_in[6];
  const float* wq_j = (const float*)d_in[7];
  const float* wq_k = (const float*)d_in[8];
  const float* bq   = (const float*)d_in[9];
  const float* wk_r = (const float*)d_in[10];
  const float* wk_i = (const float*)d_in[11];
  const float* wk_j = (const float*)d_in[12];
  const float* wk_k = (const float*)d_in[13];
  const float* bk   = (const float*)d_in[14];
  const float* wv   = (const float*)d_in[15];
  const float* bv   = (const float*)d_in[16];
  const float* wo   = (const float*)d_in[17];
  const float* bo   = (const float*)d_in[18];
  const float* thrs = (const float*)d_in[19];
  const float* dm1w = (const float*)d_in[20];
  const float* dm1b = (const float*)d_in[21];
  const float* dm2w = (const float*)d_in[22];
  const float* dm2b = (const float*)d_in[23];

  char* ws = (char*)d_ws;
  unsigned short* Wq  = (unsigned short*)(ws + ((size_t)0 << 20));
  unsigned short* Wk  = (unsigned short*)(ws + ((size_t)2 << 20));
  unsigned short* Wv  = (unsigned short*)(ws + ((size_t)4 << 20));
  unsigned short* Wo  = (unsigned short*)(ws + ((size_t)6 << 20));
  unsigned short* qbf = (unsigned short*)(ws + ((size_t)8 << 20));
  unsigned short* kbf = (unsigned short*)(ws + ((size_t)16 << 20));
  unsigned short* vT  = (unsigned short*)(ws + ((size_t)24 << 20));
  unsigned short* att = (unsigned short*)(ws + ((size_t)32 << 20));
  float* kth_g        = (float*)(ws + ((size_t)40 << 20));
  float* klm_g        = (float*)(ws + ((size_t)40 << 20) + 16384);
  unsigned int* fbits = (unsigned int*)(ws + ((size_t)40 << 20) + 32768);

  unsigned short* qcv = (unsigned short*)d_out;
  unsigned short* kcv = (unsigned short*)d_out + (size_t)MTOT * DM;
  unsigned short* vcv = att;

  hipMemsetAsync(fbits, 0, 2 * sizeof(unsigned int), stream);
  cvt_bf16<<<2048, 256, 0, stream>>>(query, key_in, value, qcv, kcv, vcv);
  prep_w<<<4096, 256, 0, stream>>>(wq_r, wq_i, wq_j, wq_k,
                                   wk_r, wk_i, wk_j, wk_k,
                                   wv, wo, Wq, Wk, Wv, Wo);
  prep_thr<<<16, 256, 0, stream>>>(density, dm1w, dm1b, dm2w, dm2b, thrs, mask,
                                   kth_g, klm_g, fbits);

  GemmArgs qkv;
  qkv.A[0] = qcv; qkv.W[0] = Wq; qkv.bias[0] = bq; qkv.out[0] = qbf; qkv.scale[0] = 0.25f; qkv.omode[0] = 0;
  qkv.A[1] = kcv; qkv.W[1] = Wk; qkv.bias[1] = bk; qkv.out[1] = kbf; qkv.scale[1] = 1.0f;  qkv.omode[1] = 0;
  qkv.A[2] = vcv; qkv.W[2] = Wv; qkv.bias[2] = bv; qkv.out[2] = vT;  qkv.scale[2] = 1.0f;  qkv.omode[2] = 1;
  gemm_bt<0><<<dim3(256, 3), 256, 0, stream>>>(qkv);

  attn_kernel<<<512, 512, 0, stream>>>(qbf, kbf, vT, kth_g, klm_g, fbits, att);

  GemmArgs og;
  og.A[0] = att; og.W[0] = Wo; og.bias[0] = bo; og.out[0] = d_out; og.scale[0] = 1.0f; og.omode[0] = 2;
  og.A[1] = att; og.W[1] = Wo; og.bias[1] = bo; og.out[1] = d_out; og.scale[1] = 1.0f; og.omode[1] = 2;
  og.A[2] = att; og.W[2] = Wo; og.bias[2] = bo; og.out[2] = d_out; og.scale[2] = 1.0f; og.omode[2] = 2;
  gemm_bt<1><<<dim3(256, 1), 256, 0, stream>>>(og);
}

// Round 7
// 227.703 us; speedup vs baseline: 1.0253x; 1.0253x over previous
//
#include <hip/hip_runtime.h>
#include <stdint.h>
#include <math.h>

#define BB 2
#define SS 2048
#define DM 1024
#define NH 16
#define HD 64
#define MTOT (BB*SS)

typedef __bf16 bf16x8 __attribute__((ext_vector_type(8)));
typedef float  f32x4  __attribute__((ext_vector_type(4)));
typedef float  f32x16 __attribute__((ext_vector_type(16)));
typedef uint32_t u32x4 __attribute__((ext_vector_type(4)));

__device__ __forceinline__ unsigned short f2bf(float f) {
  __bf16 h = (__bf16)f;                 // RNE; compiler packs to v_cvt_pk_bf16_f32
  return __builtin_bit_cast(unsigned short, h);
}

__device__ __forceinline__ bf16x8 ldsv8(const unsigned short* p) {
  return __builtin_bit_cast(bf16x8, *(const u32x4*)p);
}

__device__ __forceinline__ void gl16(const void* g, void* l) {
  __builtin_amdgcn_global_load_lds(
      (const __attribute__((address_space(1))) uint32_t*)g,
      (__attribute__((address_space(3))) uint32_t*)l, 16, 0, 0);
}

#define MFMA16(a,b,c) __builtin_amdgcn_mfma_f32_16x16x32_bf16((a),(b),(c),0,0,0)
#define MFMA32(a,b,c) __builtin_amdgcn_mfma_f32_32x32x16_bf16((a),(b),(c),0,0,0)

// gate/softmax constants
#define C_NEG5L2E  (-7.213475204444817f)   // -5*log2(e)
#define C_L2E      (1.4426950408889634f)   // log2(e)
#define C_18L2E    (25.968510736001341f)   // 18*log2(e)

// ---------------- fused prep: quaternion weights + activation cvt + thresholds ----------------
// blocks [0,4096): prep_w over 1M elems; [4096,6144): cvt over 4.19M elems; [6144,6160): thr.
__global__ __launch_bounds__(256) void prep_all(
    const float* __restrict__ wqr, const float* __restrict__ wqi,
    const float* __restrict__ wqj, const float* __restrict__ wqk,
    const float* __restrict__ wkr, const float* __restrict__ wki,
    const float* __restrict__ wkj, const float* __restrict__ wkk,
    const float* __restrict__ wv,  const float* __restrict__ wo,
    unsigned short* __restrict__ Wq, unsigned short* __restrict__ Wk,
    unsigned short* __restrict__ Wv, unsigned short* __restrict__ Wo,
    const float* __restrict__ query, const float* __restrict__ key_in,
    const float* __restrict__ value,
    unsigned short* __restrict__ qcv, unsigned short* __restrict__ kcv,
    unsigned short* __restrict__ vcv,
    const float* __restrict__ density, const float* __restrict__ dm1w,
    const float* __restrict__ dm1b, const float* __restrict__ dm2w,
    const float* __restrict__ dm2b, const float* __restrict__ thr_s,
    const int* __restrict__ mask, float* __restrict__ kth,
    float* __restrict__ klm, unsigned int* __restrict__ fbits)
{
  const int bid = blockIdx.x;
  if (bid < 4096) {
    const int idx = bid * 256 + threadIdx.x;
    const int o = idx >> 10, i = idx & 1023;
    const int br = o >> 8, bc = i >> 8;
    const int ro = o & 255, ci = i & 255;
    const int comp[4][4] = {{0,1,2,3},{1,0,3,2},{2,3,0,1},{3,2,1,0}};
    const float sgn[4][4] = {{1.f,-1.f,-1.f,-1.f},{1.f,1.f,-1.f,1.f},{1.f,1.f,1.f,-1.f},{1.f,-1.f,1.f,1.f}};
    const float* pq[4] = {wqr, wqi, wqj, wqk};
    const float* pk[4] = {wkr, wki, wkj, wkk};
    const int c_ = comp[br][bc];
    const float s_ = sgn[br][bc];
    const int pidx = ro * 256 + ci;
    Wq[idx] = f2bf(s_ * pq[c_][pidx]);
    Wk[idx] = f2bf(s_ * pk[c_][pidx]);
    Wv[idx] = f2bf(wv[idx]);
    Wo[idx] = f2bf(wo[idx]);
  } else if (bid < 6144) {
    const int i8 = ((bid - 4096) * 256 + threadIdx.x) * 8;
    {
      const float4 f0 = *(const float4*)(query + i8);
      const float4 f1 = *(const float4*)(query + i8 + 4);
      union { unsigned short us[8]; u32x4 v; } t;
      t.us[0]=f2bf(f0.x); t.us[1]=f2bf(f0.y); t.us[2]=f2bf(f0.z); t.us[3]=f2bf(f0.w);
      t.us[4]=f2bf(f1.x); t.us[5]=f2bf(f1.y); t.us[6]=f2bf(f1.z); t.us[7]=f2bf(f1.w);
      *(u32x4*)(qcv + i8) = t.v;
    }
    {
      const float4 f0 = *(const float4*)(key_in + i8);
      const float4 f1 = *(const float4*)(key_in + i8 + 4);
      union { unsigned short us[8]; u32x4 v; } t;
      t.us[0]=f2bf(f0.x); t.us[1]=f2bf(f0.y); t.us[2]=f2bf(f0.z); t.us[3]=f2bf(f0.w);
      t.us[4]=f2bf(f1.x); t.us[5]=f2bf(f1.y); t.us[6]=f2bf(f1.z); t.us[7]=f2bf(f1.w);
      *(u32x4*)(kcv + i8) = t.v;
    }
    {
      const float4 f0 = *(const float4*)(value + i8);
      const float4 f1 = *(const float4*)(value + i8 + 4);
      union { unsigned short us[8]; u32x4 v; } t;
      t.us[0]=f2bf(f0.x); t.us[1]=f2bf(f0.y); t.us[2]=f2bf(f0.z); t.us[3]=f2bf(f0.w);
      t.us[4]=f2bf(f1.x); t.us[5]=f2bf(f1.y); t.us[6]=f2bf(f1.z); t.us[7]=f2bf(f1.w);
      *(u32x4*)(vcv + i8) = t.v;
    }
  } else {
    const int i = (bid - 6144) * 256 + threadIdx.x;  // over B*S = 4096
    if (i >= BB * SS) return;
    const float x0 = density[i*3+0], x1 = density[i*3+1], x2 = density[i*3+2];
    const float base = log1pf(expf(thr_s[0]));     // softplus
    float acc = dm2b[0];
    #pragma unroll
    for (int j = 0; j < 16; ++j) {
      const float hj = dm1w[j*3+0]*x0 + dm1w[j*3+1]*x1 + dm1w[j*3+2]*x2 + dm1b[j];
      const float ge = 0.5f * hj * (1.0f + erff(hj * 0.70710678118654752f)); // exact gelu
      acc += dm2w[j] * ge;
    }
    const float thr = base + 0.1f * acc;
    const int mk = mask[i];
    kth[i] = thr * (-C_NEG5L2E);           // +5*log2e*thr
    klm[i] = mk ? 1e30f : -30.0f;
    const unsigned long long any = __ballot(mk == 0);
    if ((threadIdx.x & 63) == 0 && any)
      atomicOr(&fbits[i >> 11], 1u << ((i >> 6) & 31));  // per-64-key-tile mask flag
  }
}

// ---------------- GEMM: C(M=4096,N=1024) = A(M,K=1024) @ W(N,K)^T + bias ----------------
struct GemmArgs {
  const unsigned short* A[3];
  const unsigned short* W[3];
  const float* bias[3];
  void* out[3];
  float scale[3];
  int omode[3];
};

template<int DB>
__global__ __launch_bounds__(256) void gemm_bt(GemmArgs args)
{
  __shared__ __align__(16) unsigned short lA[DB + 1][128*64];
  __shared__ __align__(16) unsigned short lB[DB + 1][128*64];
  const int z = blockIdx.y;
  const int tid = threadIdx.x;
  const int wid = tid >> 6, lane = tid & 63;
  const int l15 = lane & 15, l4 = lane >> 4;
  const int bm = blockIdx.x & 31, bn = blockIdx.x >> 5;   // XCD-aware decode
  const int row0 = bm * 128, col0 = bn * 128;
  const int wm = (wid >> 1) * 64, wn = (wid & 1) * 64;

  const unsigned short* gA[4];
  const unsigned short* gB[4];
  #pragma unroll
  for (int i = 0; i < 4; ++i) {
    const int c = (wid * 4 + i) * 64 + lane;
    const int r = c >> 3, jx = c & 7, j = jx ^ (r & 7);
    gA[i] = args.A[z] + (row0 + r) * 1024 + j * 8;
    gB[i] = args.W[z] + (col0 + r) * 1024 + j * 8;
  }

  f32x4 acc[4][4];
  #pragma unroll
  for (int i = 0; i < 4; ++i)
    #pragma unroll
    for (int j = 0; j < 4; ++j) acc[i][j] = (f32x4){0.f,0.f,0.f,0.f};

  #pragma unroll
  for (int i = 0; i < 4; ++i) {
    gl16(gA[i], &lA[0][(wid * 4 + i) * 512]);
    gl16(gB[i], &lB[0][(wid * 4 + i) * 512]);
  }
  if (DB) __syncthreads();

  for (int kt = 0; kt < 16; ++kt) {
    const int cb = DB ? (kt & 1) : 0;
    if (DB) {
      if (kt < 15) {
        const int nb = cb ^ 1, k0 = (kt + 1) * 64;
        #pragma unroll
        for (int i = 0; i < 4; ++i) {
          gl16(gA[i] + k0, &lA[nb][(wid * 4 + i) * 512]);
          gl16(gB[i] + k0, &lB[nb][(wid * 4 + i) * 512]);
        }
      }
    } else {
      if (kt > 0) {
        const int k0 = kt * 64;
        #pragma unroll
        for (int i = 0; i < 4; ++i) {
          gl16(gA[i] + k0, &lA[0][(wid * 4 + i) * 512]);
          gl16(gB[i] + k0, &lB[0][(wid * 4 + i) * 512]);
        }
      }
      __syncthreads();
    }
    #pragma unroll
    for (int kk = 0; kk < 2; ++kk) {
      const int kl = kk * 32 + l4 * 8;
      bf16x8 af[4], bfb[4];
      #pragma unroll
      for (int mi = 0; mi < 4; ++mi) {
        const int r = wm + mi * 16 + l15;
        af[mi] = ldsv8(&lA[cb][r * 64 + (kl ^ ((r & 7) << 3))]);
      }
      #pragma unroll
      for (int nj = 0; nj < 4; ++nj) {
        const int r = wn + nj * 16 + l15;
        bfb[nj] = ldsv8(&lB[cb][r * 64 + (kl ^ ((r & 7) << 3))]);
      }
      #pragma unroll
      for (int mi = 0; mi < 4; ++mi)
        #pragma unroll
        for (int nj = 0; nj < 4; ++nj)
          acc[mi][nj] = MFMA16(af[mi], bfb[nj], acc[mi][nj]);
    }
    __syncthreads();
  }

  const int om = args.omode[z];
  const float sc = args.scale[z];
  void* Cptr = args.out[z];
  #pragma unroll
  for (int nj = 0; nj < 4; ++nj) {
    const int c = col0 + wn + nj * 16 + l15;
    const float bv_ = args.bias[z][c];
    #pragma unroll
    for (int mi = 0; mi < 4; ++mi) {
      const int rb = row0 + wm + mi * 16 + l4 * 4;
      #pragma unroll
      for (int e = 0; e < 4; ++e) {
        const float val = (acc[mi][nj][e] + bv_) * sc;
        const int r = rb + e;
        if (om == 0) {
          ((unsigned short*)Cptr)[r * 1024 + c] = f2bf(val);
        } else if (om == 2) {
          ((float*)Cptr)[r * 1024 + c] = val;
        } else {
          const int h = c >> 6, d = c & 63, b = r >> 11, s = r & 2047;
          ((unsigned short*)Cptr)[((h * BB + b) * HD + d) * SS + s] = f2bf(val);
        }
      }
    }
  }
}

// ---------------- flash attention: 32x32 MFMA, swapped QK^T, in-register P ----------------
// 512 threads = 8 waves = 4 row-groups(32 rows) x 2 key-parities(32 keys of each 64-key pair).
// S^T = mfma(A=K, B=Q): lane holds one q-row (lane&31), 16 reg-mapped keys.
// P assembled in-register (cvt_pk + shfl_xor 32). Fixed-max softmax. LDS-limited 4 blocks/CU;
// launch_bounds min-waves=2 keeps the VGPR cap high (R6's (512,4) caused scratch spills).
__global__ __launch_bounds__(512, 2) void attn_kernel(
    const unsigned short* __restrict__ qg, const unsigned short* __restrict__ kg,
    const unsigned short* __restrict__ vT, const float* __restrict__ kth_g,
    const float* __restrict__ klm_g, const unsigned int* __restrict__ fbits,
    unsigned short* __restrict__ outg)
{
  // buffers: 2 x { K 8KB (2 parity x 16row x 256B), V 8KB, kth 256B, klm 256B } = 33792 B
  // merge phase reuses: lsums 2KB @0, dinv 512B @2048, O-dump 32KB @4096  -> 36864 B total
  __shared__ __align__(16) unsigned char smem[36864];
  const int tid = threadIdx.x;
  const int lane = tid & 63, wid = tid >> 6;
  const int l31 = lane & 31, l5 = lane >> 5;
  const int rg = wid >> 1, par = wid & 1;
  const int hb = blockIdx.x & 31, qc = blockIdx.x >> 5;   // XCD: same (h,b) -> same XCD
  const int h = hb >> 1, b = hb & 1;
  const int qr0 = qc * 128 + rg * 32;

  const unsigned short* kbase = kg + (size_t)(b * SS) * DM + h * HD;
  const unsigned short* vbase = vT + (size_t)((h * BB + b) * HD) * SS;
  const float* kthb = kth_g + b * SS;
  const float* klmb = klm_g + b * SS;
  const unsigned int fb = fbits[b];

  // staging addressing (per 64-key pair): K: key sk, hd-chunk sj. V: d sk, key-chunk sj.
  const int sk = tid >> 3, sj = tid & 7;
  const int kp = sk >> 5, kkl = sk & 31;
  const int kdst = kp*4096 + (kkl>>1)*256 + (((((kkl&1)<<3)|sj)) ^ ((kkl>>1)&15))*16;
  const int vp = sj >> 2, vjj = sj & 3;
  const int vdst = 8192 + vp*4096 + (sk>>2)*256 + (((((sk&3)<<2)|vjj)) ^ ((sk>>2)&15))*16;
  const unsigned short* kgsrc = kbase + sk * DM + sj * 8;
  const unsigned short* vgsrc = vbase + (size_t)sk * SS + sj * 8;

  // Q B-fragments (col=qrow=lane&31, k=hd ks*16 + l5*8); Q pre-scaled by 0.25
  bf16x8 bq[4];
  {
    const unsigned short* qs = qg + (size_t)(b * SS + qr0 + l31) * DM + h * HD + l5 * 8;
    #pragma unroll
    for (int ks = 0; ks < 4; ++ks)
      bq[ks] = __builtin_bit_cast(bf16x8, *(const u32x4*)(qs + ks * 16));
  }
  const float limq = klmb[qr0 + l31];   // per-lane q-row mask bound

  f32x16 O0 = {}, O1 = {};
  float lsum = 0.f;

  // prologue: stage pair 0
  u32x4 kr = *(const u32x4*)kgsrc;
  u32x4 vr = *(const u32x4*)vgsrc;
  f32x4 tk, tl;
  if (tid < 16)      tk = *(const f32x4*)(kthb + tid * 4);
  else if (tid < 32) tl = *(const f32x4*)(klmb + (tid - 16) * 4);
  *(u32x4*)(smem + kdst) = kr;
  *(u32x4*)(smem + vdst) = vr;
  if (tid < 16)      *(f32x4*)(smem + 16384 + tid * 16) = tk;
  else if (tid < 32) *(f32x4*)(smem + 16640 + (tid - 16) * 16) = tl;
  __syncthreads();

  for (int pr = 0; pr < 32; ++pr) {
    unsigned char* cb = smem + (pr & 1) * 16896;
    const int n0 = pr * 64;

    // prefetch next pair into regs
    if (pr < 31) {
      kr = *(const u32x4*)(kgsrc + (size_t)(n0 + 64) * DM);
      vr = *(const u32x4*)(vgsrc + n0 + 64);
      if (tid < 16)      tk = *(const f32x4*)(kthb + n0 + 64 + tid * 4);
      else if (tid < 32) tl = *(const f32x4*)(klmb + n0 + 64 + (tid - 16) * 4);
    }

    // per-key kth (broadcast reads: 2 addrs per wave)
    f32x4 kth4[4];
    #pragma unroll
    for (int g2 = 0; g2 < 4; ++g2)
      kth4[g2] = *(const f32x4*)(cb + 16384 + par*128 + g2*32 + l5*16);

    // S^T = K @ Q : lane = qrow (col), reg-mapped keys (rows)
    f32x16 S = {};
    {
      const unsigned char* Kb = cb + par * 4096;
      const int krow = l31 >> 1;
      __builtin_amdgcn_s_setprio(1);
      #pragma unroll
      for (int ks = 0; ks < 4; ++ks) {
        const int slot = ((((l31 & 1) << 3) | (ks*2 + l5)) ^ (krow & 15));
        bf16x8 ka = __builtin_bit_cast(bf16x8, *(const u32x4*)(Kb + krow*256 + slot*16));
        S = MFMA32(ka, bq[ks], S);
      }
      __builtin_amdgcn_s_setprio(0);
    }

    // spike gate + mask + fixed-max softmax numerator; key(r) = (r&3)+8*(r>>2)+4*l5
    // fused gate -> bf16 pack (no p[16] array: lower register pressure)
    unsigned int c[8];
    const bool fast = !((fb >> pr) & 1);
    f32x4 klm4[4];
    if (!fast) {
      #pragma unroll
      for (int g2 = 0; g2 < 4; ++g2)
        klm4[g2] = *(const f32x4*)(cb + 16640 + par*128 + g2*32 + l5*16);
    }
    #pragma unroll
    for (int i = 0; i < 8; ++i) {
      float pv2[2];
      #pragma unroll
      for (int q2 = 0; q2 < 2; ++q2) {
        const int r = 2*i + q2;
        float s = fminf(fmaxf(S[r], -6.f), 6.f);
        const float t = __builtin_amdgcn_exp2f(fmaf(s, C_NEG5L2E, kth4[r>>2][r&3]));
        const float g = __builtin_amdgcn_rcpf(1.f + t);
        float md = fmaf(s + s, g, s);
        md = fast ? fminf(md, limq)
                  : fminf(md, fminf(klm4[r>>2][r&3], limq));
        const float pv = __builtin_amdgcn_exp2f(fmaf(md, C_L2E, -C_18L2E));
        pv2[q2] = pv;
        lsum += pv;
      }
      union { unsigned short us[2]; unsigned int u; } t2;
      t2.us[0] = f2bf(pv2[0]); t2.us[1] = f2bf(pv2[1]);
      c[i] = t2.u;
    }

    // assemble PV A-fragments in-register
    unsigned int cp[8];
    #pragma unroll
    for (int i = 0; i < 8; ++i) cp[i] = (unsigned int)__shfl_xor((int)c[i], 32);
    bf16x8 pa0, pa1;
    {
      union { unsigned int u[4]; bf16x8 v; } fa;
      fa.u[0] = l5 ? cp[2] : c[0];
      fa.u[1] = l5 ? cp[3] : c[1];
      fa.u[2] = l5 ? c[2]  : cp[0];
      fa.u[3] = l5 ? c[3]  : cp[1];
      pa0 = fa.v;
      fa.u[0] = l5 ? cp[6] : c[4];
      fa.u[1] = l5 ? cp[7] : c[5];
      fa.u[2] = l5 ? c[6]  : cp[4];
      fa.u[3] = l5 ? c[7]  : cp[5];
      pa1 = fa.v;
    }

    // PV: O[dt] += P @ V  (B-frag: col=d=lane&31, k=keys ks2*16 + l5*8)
    {
      const unsigned char* Vb = cb + 8192 + par * 4096;
      __builtin_amdgcn_s_setprio(1);
      #pragma unroll
      for (int dt = 0; dt < 2; ++dt) {
        const int vrow = dt*8 + (l31 >> 2);
        #pragma unroll
        for (int ks2 = 0; ks2 < 2; ++ks2) {
          const int slot = ((((l31 & 3) << 2) | (ks2*2 + l5)) ^ (vrow & 15));
          bf16x8 bv = __builtin_bit_cast(bf16x8, *(const u32x4*)(Vb + vrow*256 + slot*16));
          if (dt == 0) O0 = MFMA32(ks2 ? pa1 : pa0, bv, O0);
          else         O1 = MFMA32(ks2 ? pa1 : pa0, bv, O1);
        }
      }
      __builtin_amdgcn_s_setprio(0);
    }

    // write staged next pair
    if (pr < 31) {
      unsigned char* nb = smem + ((pr + 1) & 1) * 16896;
      *(u32x4*)(nb + kdst) = kr;
      *(u32x4*)(nb + vdst) = vr;
      if (tid < 16)      *(f32x4*)(nb + 16384 + tid * 16) = tk;
      else if (tid < 32) *(f32x4*)(nb + 16640 + (tid - 16) * 16) = tl;
    }
    __syncthreads();
  }

  // ---- merge parity partials; normalize; store ----
  float* xf = (float*)smem;
  xf[(rg*2 + par)*64 + lane] = lsum;
  __syncthreads();
  float* dinv = (float*)(smem + 2048);
  if (par == 0 && lane < 32) {
    const float* ls0 = xf + rg * 128;
    const float den = ls0[lane] + ls0[32 + lane] + ls0[64 + lane] + ls0[96 + lane];
    dinv[rg*32 + lane] = __builtin_amdgcn_rcpf(den);
  }
  __syncthreads();
  float* od = (float*)(smem + 4096) + rg * 2048;
  if (par) {
    #pragma unroll
    for (int r = 0; r < 16; ++r) {
      od[r*64 + lane]        = O0[r];
      od[(16 + r)*64 + lane] = O1[r];
    }
  }
  __syncthreads();
  if (!par) {
    unsigned short* ob = outg + (size_t)(b * SS + qr0) * DM + h * HD;
    #pragma unroll
    for (int r = 0; r < 16; ++r) {
      const int row = (r & 3) + 8*(r >> 2) + 4*l5;
      const float di = dinv[rg*32 + row];
      const float v0 = O0[r] + od[r*64 + lane];
      const float v1 = O1[r] + od[(16 + r)*64 + lane];
      ob[(size_t)row * DM + l31]      = f2bf(v0 * di);
      ob[(size_t)row * DM + 32 + l31] = f2bf(v1 * di);
    }
  }
}

// ---------------- launcher ----------------
extern "C" void kernel_launch(void* const* d_in, const int* in_sizes, int n_in,
                              void* d_out, int out_size, void* d_ws, size_t ws_size,
                              hipStream_t stream)
{
  const float* query   = (const float*)d_in[0];
  const float* key_in  = (const float*)d_in[1];
  const float* value   = (const float*)d_in[2];
  const int*   mask    = (const int*)d_in[3];
  const float* density = (const float*)d_in[4];
  const float* wq_r = (const float*)d_in[5];
  const float* wq_i = (const float*)d_in[6];
  const float* wq_j = (const float*)d_in[7];
  const float* wq_k = (const float*)d_in[8];
  const float* bq   = (const float*)d_in[9];
  const float* wk_r = (const float*)d_in[10];
  const float* wk_i = (const float*)d_in[11];
  const float* wk_j = (const float*)d_in[12];
  const float* wk_k = (const float*)d_in[13];
  const float* bk   = (const float*)d_in[14];
  const float* wv   = (const float*)d_in[15];
  const float* bv   = (const float*)d_in[16];
  const float* wo   = (const float*)d_in[17];
  const float* bo   = (const float*)d_in[18];
  const float* thrs = (const float*)d_in[19];
  const float* dm1w = (const float*)d_in[20];
  const float* dm1b = (const float*)d_in[21];
  const float* dm2w = (const float*)d_in[22];
  const float* dm2b = (const float*)d_in[23];

  char* ws = (char*)d_ws;
  unsigned short* Wq  = (unsigned short*)(ws + ((size_t)0 << 20));
  unsigned short* Wk  = (unsigned short*)(ws + ((size_t)2 << 20));
  unsigned short* Wv  = (unsigned short*)(ws + ((size_t)4 << 20));
  unsigned short* Wo  = (unsigned short*)(ws + ((size_t)6 << 20));
  unsigned short* qbf = (unsigned short*)(ws + ((size_t)8 << 20));
  unsigned short* kbf = (unsigned short*)(ws + ((size_t)16 << 20));
  unsigned short* vT  = (unsigned short*)(ws + ((size_t)24 << 20));
  unsigned short* att = (unsigned short*)(ws + ((size_t)32 << 20));
  float* kth_g        = (float*)(ws + ((size_t)40 << 20));
  float* klm_g        = (float*)(ws + ((size_t)40 << 20) + 16384);
  unsigned int* fbits = (unsigned int*)(ws + ((size_t)40 << 20) + 32768);

  unsigned short* qcv = (unsigned short*)d_out;
  unsigned short* kcv = (unsigned short*)d_out + (size_t)MTOT * DM;
  unsigned short* vcv = att;

  hipMemsetAsync(fbits, 0, 2 * sizeof(unsigned int), stream);
  prep_all<<<6160, 256, 0, stream>>>(
      wq_r, wq_i, wq_j, wq_k, wk_r, wk_i, wk_j, wk_k, wv, wo,
      Wq, Wk, Wv, Wo,
      query, key_in, value, qcv, kcv, vcv,
      density, dm1w, dm1b, dm2w, dm2b, thrs, mask, kth_g, klm_g, fbits);

  GemmArgs qkv;
  qkv.A[0] = qcv; qkv.W[0] = Wq; qkv.bias[0] = bq; qkv.out[0] = qbf; qkv.scale[0] = 0.25f; qkv.omode[0] = 0;
  qkv.A[1] = kcv; qkv.W[1] = Wk; qkv.bias[1] = bk; qkv.out[1] = kbf; qkv.scale[1] = 1.0f;  qkv.omode[1] = 0;
  qkv.A[2] = vcv; qkv.W[2] = Wv; qkv.bias[2] = bv; qkv.out[2] = vT;  qkv.scale[2] = 1.0f;  qkv.omode[2] = 1;
  gemm_bt<0><<<dim3(256, 3), 256, 0, stream>>>(qkv);

  attn_kernel<<<512, 512, 0, stream>>>(qbf, kbf, vT, kth_g, klm_g, fbits, att);

  GemmArgs og;
  og.A[0] = att; og.W[0] = Wo; og.bias[0] = bo; og.out[0] = d_out; og.scale[0] = 1.0f; og.omode[0] = 2;
  og.A[1] = att; og.W[1] = Wo; og.bias[1] = bo; og.out[1] = d_out; og.scale[1] = 1.0f; og.omode[1] = 2;
  og.A[2] = att; og.W[2] = Wo; og.bias[2] = bo; og.out[2] = d_out; og.scale[2] = 1.0f; og.omode[2] = 2;
  gemm_bt<1><<<dim3(256, 1), 256, 0, stream>>>(og);
}

// Round 8
// 182.129 us; speedup vs baseline: 1.2819x; 1.2502x over previous
//
#include <hip/hip_runtime.h>
#include <stdint.h>
#include <math.h>

#define BB 2
#define SS 2048
#define DM 1024
#define NH 16
#define HD 64
#define MTOT (BB*SS)

typedef __bf16 bf16x8 __attribute__((ext_vector_type(8)));
typedef float  f32x4  __attribute__((ext_vector_type(4)));
typedef uint32_t u32x4 __attribute__((ext_vector_type(4)));

__device__ __forceinline__ unsigned short f2bf(float f) {
  __bf16 h = (__bf16)f;                 // RNE; compiler packs to v_cvt_pk_bf16_f32
  return __builtin_bit_cast(unsigned short, h);
}

__device__ __forceinline__ bf16x8 ldsv8(const unsigned short* p) {
  return __builtin_bit_cast(bf16x8, *(const u32x4*)p);
}

__device__ __forceinline__ void gl16(const void* g, void* l) {
  __builtin_amdgcn_global_load_lds(
      (const __attribute__((address_space(1))) uint32_t*)g,
      (__attribute__((address_space(3))) uint32_t*)l, 16, 0, 0);
}

#define MFMA16(a,b,c) __builtin_amdgcn_mfma_f32_16x16x32_bf16((a),(b),(c),0,0,0)

// gate/softmax constants
#define C_NEG5L2E  (-7.213475204444817f)   // -5*log2(e)
#define C_L2E      (1.4426950408889634f)   // log2(e)
#define C_18L2E    (25.968510736001341f)   // 18*log2(e)

// ---------------- fused prep: quaternion weights + activation cvt + thresholds ----------------
// blocks [0,512): prep_w (8 elem/thread over 1M); [512,2560): cvt (8/thread over 4.19M); [2560,2576): thr.
__global__ __launch_bounds__(256) void prep_all(
    const float* __restrict__ wqr, const float* __restrict__ wqi,
    const float* __restrict__ wqj, const float* __restrict__ wqk,
    const float* __restrict__ wkr, const float* __restrict__ wki,
    const float* __restrict__ wkj, const float* __restrict__ wkk,
    const float* __restrict__ wv,  const float* __restrict__ wo,
    unsigned short* __restrict__ Wq, unsigned short* __restrict__ Wk,
    unsigned short* __restrict__ Wv, unsigned short* __restrict__ Wo,
    const float* __restrict__ query, const float* __restrict__ key_in,
    const float* __restrict__ value,
    unsigned short* __restrict__ qcv, unsigned short* __restrict__ kcv,
    unsigned short* __restrict__ vcv,
    const float* __restrict__ density, const float* __restrict__ dm1w,
    const float* __restrict__ dm1b, const float* __restrict__ dm2w,
    const float* __restrict__ dm2b, const float* __restrict__ thr_s,
    const int* __restrict__ mask, float2* __restrict__ klim)
{
  const int bid = blockIdx.x;
  if (bid < 512) {
    const int idx = (bid * 256 + threadIdx.x) * 8;      // 8 consecutive elems, same row/block
    const int o = idx >> 10, i = idx & 1023;
    const int br = o >> 8, bc = i >> 8;
    const int ro = o & 255, ci = i & 255;
    const int comp[4][4] = {{0,1,2,3},{1,0,3,2},{2,3,0,1},{3,2,1,0}};
    const float sgn[4][4] = {{1.f,-1.f,-1.f,-1.f},{1.f,1.f,-1.f,1.f},{1.f,1.f,1.f,-1.f},{1.f,-1.f,1.f,1.f}};
    const float* pq[4] = {wqr, wqi, wqj, wqk};
    const float* pk[4] = {wkr, wki, wkj, wkk};
    const int c_ = comp[br][bc];
    const float s_ = sgn[br][bc];
    const float* qsrc = pq[c_] + ro * 256 + ci;
    const float* ksrc = pk[c_] + ro * 256 + ci;
    {
      const float4 f0 = *(const float4*)qsrc;
      const float4 f1 = *(const float4*)(qsrc + 4);
      union { unsigned short us[8]; u32x4 v; } t;
      t.us[0]=f2bf(s_*f0.x); t.us[1]=f2bf(s_*f0.y); t.us[2]=f2bf(s_*f0.z); t.us[3]=f2bf(s_*f0.w);
      t.us[4]=f2bf(s_*f1.x); t.us[5]=f2bf(s_*f1.y); t.us[6]=f2bf(s_*f1.z); t.us[7]=f2bf(s_*f1.w);
      *(u32x4*)(Wq + idx) = t.v;
    }
    {
      const float4 f0 = *(const float4*)ksrc;
      const float4 f1 = *(const float4*)(ksrc + 4);
      union { unsigned short us[8]; u32x4 v; } t;
      t.us[0]=f2bf(s_*f0.x); t.us[1]=f2bf(s_*f0.y); t.us[2]=f2bf(s_*f0.z); t.us[3]=f2bf(s_*f0.w);
      t.us[4]=f2bf(s_*f1.x); t.us[5]=f2bf(s_*f1.y); t.us[6]=f2bf(s_*f1.z); t.us[7]=f2bf(s_*f1.w);
      *(u32x4*)(Wk + idx) = t.v;
    }
    {
      const float4 f0 = *(const float4*)(wv + idx);
      const float4 f1 = *(const float4*)(wv + idx + 4);
      union { unsigned short us[8]; u32x4 v; } t;
      t.us[0]=f2bf(f0.x); t.us[1]=f2bf(f0.y); t.us[2]=f2bf(f0.z); t.us[3]=f2bf(f0.w);
      t.us[4]=f2bf(f1.x); t.us[5]=f2bf(f1.y); t.us[6]=f2bf(f1.z); t.us[7]=f2bf(f1.w);
      *(u32x4*)(Wv + idx) = t.v;
    }
    {
      const float4 f0 = *(const float4*)(wo + idx);
      const float4 f1 = *(const float4*)(wo + idx + 4);
      union { unsigned short us[8]; u32x4 v; } t;
      t.us[0]=f2bf(f0.x); t.us[1]=f2bf(f0.y); t.us[2]=f2bf(f0.z); t.us[3]=f2bf(f0.w);
      t.us[4]=f2bf(f1.x); t.us[5]=f2bf(f1.y); t.us[6]=f2bf(f1.z); t.us[7]=f2bf(f1.w);
      *(u32x4*)(Wo + idx) = t.v;
    }
  } else if (bid < 2560) {
    const int i8 = ((bid - 512) * 256 + threadIdx.x) * 8;
    {
      const float4 f0 = *(const float4*)(query + i8);
      const float4 f1 = *(const float4*)(query + i8 + 4);
      union { unsigned short us[8]; u32x4 v; } t;
      t.us[0]=f2bf(f0.x); t.us[1]=f2bf(f0.y); t.us[2]=f2bf(f0.z); t.us[3]=f2bf(f0.w);
      t.us[4]=f2bf(f1.x); t.us[5]=f2bf(f1.y); t.us[6]=f2bf(f1.z); t.us[7]=f2bf(f1.w);
      *(u32x4*)(qcv + i8) = t.v;
    }
    {
      const float4 f0 = *(const float4*)(key_in + i8);
      const float4 f1 = *(const float4*)(key_in + i8 + 4);
      union { unsigned short us[8]; u32x4 v; } t;
      t.us[0]=f2bf(f0.x); t.us[1]=f2bf(f0.y); t.us[2]=f2bf(f0.z); t.us[3]=f2bf(f0.w);
      t.us[4]=f2bf(f1.x); t.us[5]=f2bf(f1.y); t.us[6]=f2bf(f1.z); t.us[7]=f2bf(f1.w);
      *(u32x4*)(kcv + i8) = t.v;
    }
    {
      const float4 f0 = *(const float4*)(value + i8);
      const float4 f1 = *(const float4*)(value + i8 + 4);
      union { unsigned short us[8]; u32x4 v; } t;
      t.us[0]=f2bf(f0.x); t.us[1]=f2bf(f0.y); t.us[2]=f2bf(f0.z); t.us[3]=f2bf(f0.w);
      t.us[4]=f2bf(f1.x); t.us[5]=f2bf(f1.y); t.us[6]=f2bf(f1.z); t.us[7]=f2bf(f1.w);
      *(u32x4*)(vcv + i8) = t.v;
    }
  } else {
    const int i = (bid - 2560) * 256 + threadIdx.x;  // over B*S = 4096
    if (i >= BB * SS) return;
    const float x0 = density[i*3+0], x1 = density[i*3+1], x2 = density[i*3+2];
    const float base = log1pf(expf(thr_s[0]));     // softplus
    float acc = dm2b[0];
    #pragma unroll
    for (int j = 0; j < 16; ++j) {
      const float hj = dm1w[j*3+0]*x0 + dm1w[j*3+1]*x1 + dm1w[j*3+2]*x2 + dm1b[j];
      const float ge = 0.5f * hj * (1.0f + erff(hj * 0.70710678118654752f)); // exact gelu
      acc += dm2w[j] * ge;
    }
    const float thr = base + 0.1f * acc;
    klim[i] = make_float2(thr * (-C_NEG5L2E),          // +5*log2e*thr (exp2 arg offset)
                          mask[i] ? 1e30f : -30.0f);   // mask limit for min
  }
}

// ---------------- GEMM: C(M=4096,N=1024) = A(M,K=1024) @ W(N,K)^T + bias ----------------
struct GemmArgs {
  const unsigned short* A[3];
  const unsigned short* W[3];
  const float* bias[3];
  void* out[3];
  float scale[3];
  int omode[3];
};

template<int DB>
__global__ __launch_bounds__(256) void gemm_bt(GemmArgs args)
{
  __shared__ __align__(16) unsigned short lA[DB + 1][128*64];
  __shared__ __align__(16) unsigned short lB[DB + 1][128*64];
  const int z = blockIdx.y;
  const int tid = threadIdx.x;
  const int wid = tid >> 6, lane = tid & 63;
  const int l15 = lane & 15, l4 = lane >> 4;
  const int bm = blockIdx.x & 31, bn = blockIdx.x >> 5;   // XCD-aware decode
  const int row0 = bm * 128, col0 = bn * 128;
  const int wm = (wid >> 1) * 64, wn = (wid & 1) * 64;

  const unsigned short* gA[4];
  const unsigned short* gB[4];
  #pragma unroll
  for (int i = 0; i < 4; ++i) {
    const int c = (wid * 4 + i) * 64 + lane;
    const int r = c >> 3, jx = c & 7, j = jx ^ (r & 7);
    gA[i] = args.A[z] + (row0 + r) * 1024 + j * 8;
    gB[i] = args.W[z] + (col0 + r) * 1024 + j * 8;
  }

  f32x4 acc[4][4];
  #pragma unroll
  for (int i = 0; i < 4; ++i)
    #pragma unroll
    for (int j = 0; j < 4; ++j) acc[i][j] = (f32x4){0.f,0.f,0.f,0.f};

  #pragma unroll
  for (int i = 0; i < 4; ++i) {
    gl16(gA[i], &lA[0][(wid * 4 + i) * 512]);
    gl16(gB[i], &lB[0][(wid * 4 + i) * 512]);
  }
  if (DB) __syncthreads();

  for (int kt = 0; kt < 16; ++kt) {
    const int cb = DB ? (kt & 1) : 0;
    if (DB) {
      if (kt < 15) {
        const int nb = cb ^ 1, k0 = (kt + 1) * 64;
        #pragma unroll
        for (int i = 0; i < 4; ++i) {
          gl16(gA[i] + k0, &lA[nb][(wid * 4 + i) * 512]);
          gl16(gB[i] + k0, &lB[nb][(wid * 4 + i) * 512]);
        }
      }
    } else {
      if (kt > 0) {
        const int k0 = kt * 64;
        #pragma unroll
        for (int i = 0; i < 4; ++i) {
          gl16(gA[i] + k0, &lA[0][(wid * 4 + i) * 512]);
          gl16(gB[i] + k0, &lB[0][(wid * 4 + i) * 512]);
        }
      }
      __syncthreads();
    }
    #pragma unroll
    for (int kk = 0; kk < 2; ++kk) {
      const int kl = kk * 32 + l4 * 8;
      bf16x8 af[4], bfb[4];
      #pragma unroll
      for (int mi = 0; mi < 4; ++mi) {
        const int r = wm + mi * 16 + l15;
        af[mi] = ldsv8(&lA[cb][r * 64 + (kl ^ ((r & 7) << 3))]);
      }
      #pragma unroll
      for (int nj = 0; nj < 4; ++nj) {
        const int r = wn + nj * 16 + l15;
        bfb[nj] = ldsv8(&lB[cb][r * 64 + (kl ^ ((r & 7) << 3))]);
      }
      #pragma unroll
      for (int mi = 0; mi < 4; ++mi)
        #pragma unroll
        for (int nj = 0; nj < 4; ++nj)
          acc[mi][nj] = MFMA16(af[mi], bfb[nj], acc[mi][nj]);
    }
    __syncthreads();
  }

  const int om = args.omode[z];
  const float sc = args.scale[z];
  void* Cptr = args.out[z];
  #pragma unroll
  for (int nj = 0; nj < 4; ++nj) {
    const int c = col0 + wn + nj * 16 + l15;
    const float bv_ = args.bias[z][c];
    #pragma unroll
    for (int mi = 0; mi < 4; ++mi) {
      const int rb = row0 + wm + mi * 16 + l4 * 4;
      #pragma unroll
      for (int e = 0; e < 4; ++e) {
        const float val = (acc[mi][nj][e] + bv_) * sc;
        const int r = rb + e;
        if (om == 0) {
          ((unsigned short*)Cptr)[r * 1024 + c] = f2bf(val);
        } else if (om == 2) {
          ((float*)Cptr)[r * 1024 + c] = val;
        } else {
          const int h = c >> 6, d = c & 63, b = r >> 11, s = r & 2047;
          ((unsigned short*)Cptr)[((h * BB + b) * HD + d) * SS + s] = f2bf(val);
        }
      }
    }
  }
}

// ---------------- flash attention with spike gate: split-K wave pairs (R5 structure) ----------------
// 512 threads = 8 waves = 4 row-groups x 2 key-parities. Per pair-interval (64 keys),
// wave (rg,par) computes the 32-key tile of its parity; partials merged at the end
// (valid because softmax uses a fixed max).
__global__ __launch_bounds__(512) void attn_kernel(
    const unsigned short* __restrict__ qg, const unsigned short* __restrict__ kg,
    const unsigned short* __restrict__ vT, const float2* __restrict__ klim,
    const int* __restrict__ mask, unsigned short* __restrict__ outg)
{
  __shared__ __align__(16) unsigned short smem[20480];   // 40 KB
  unsigned short* lK = smem;            // [pairbuf 2][tile 2][32 key-rows][64 hd]
  unsigned short* lV = smem + 8192;     // [pairbuf 2][tile 2][64 d-rows][32 keys]
  unsigned short* lP = smem + 16384;    // [wave 8][16 qrows][32 keys]

  const int tid = threadIdx.x;
  const int wid = tid >> 6, lane = tid & 63;
  const int l15 = lane & 15, l4 = lane >> 4;
  const int rg = wid >> 1, par = wid & 1;
  const int hb = blockIdx.x & 31, qb = blockIdx.x >> 5;  // XCD: same (h,b) -> same XCD
  const int h = hb >> 1, b = hb & 1;
  const int qr0 = qb * 64 + rg * 16;

  // staging: each thread 1 K-chunk + 1 V-chunk of the 64-key pair
  const int kcr = tid >> 3, kcj = (tid & 7) * 8;         // K: key row, hd col
  const int vcd = tid >> 3, vck = (tid & 7) * 8;         // V: d row, key col
  const int kdst = (kcr >> 5) * 2048 + (kcr & 31) * 64 + (kcj ^ ((((kcr & 31) >> 1) & 7) << 3));
  const int vdst = (vck >> 5) * 2048 + vcd * 32 + ((vck & 31) ^ ((vcd & 3) << 3));

  const unsigned short* kbase = kg + (b * SS) * DM + h * HD;
  const unsigned short* vbase = vT + ((h * BB + b) * HD) * SS;
  const float2* klimb = klim + b * SS;

  // Q fragments (A-frag: row=lane%16, k=(lane>>4)*8); Q pre-scaled by 0.25
  bf16x8 aq[2];
  {
    const unsigned short* qs = qg + (b * SS + qr0 + l15) * DM + h * HD + l4 * 8;
    aq[0] = __builtin_bit_cast(bf16x8, *(const u32x4*)qs);
    aq[1] = __builtin_bit_cast(bf16x8, *(const u32x4*)(qs + 32));
  }
  float limq[4];
  #pragma unroll
  for (int e = 0; e < 4; ++e)
    limq[e] = mask[b * SS + qr0 + l4 * 4 + e] ? 1e30f : -30.0f;

  float lrun[4] = {0.f, 0.f, 0.f, 0.f};
  f32x4 o[4];
  #pragma unroll
  for (int d = 0; d < 4; ++d) o[d] = (f32x4){0.f,0.f,0.f,0.f};

  unsigned short* lPw = lP + wid * 512;

  // prologue: stage pair 0
  u32x4 kr = *(const u32x4*)(kbase + kcr * DM + kcj);
  u32x4 vr = *(const u32x4*)(vbase + vcd * SS + vck);
  *(u32x4*)&lK[kdst] = kr;
  *(u32x4*)&lV[vdst] = vr;
  __syncthreads();

  for (int pr = 0; pr < 32; ++pr) {
    const int cur = pr & 1;
    const unsigned short* lKt = lK + cur * 4096 + par * 2048;
    const unsigned short* lVt = lV + cur * 4096 + par * 2048;
    const int n0 = pr * 64 + par * 32;

    if (pr < 31) {
      const int nn = (pr + 1) * 64;
      kr = *(const u32x4*)(kbase + (nn + kcr) * DM + kcj);
      vr = *(const u32x4*)(vbase + vcd * SS + nn + vck);
    }

    const float4 klA = *(const float4*)(klimb + n0 + 2 * l15);   // keys 2l15, 2l15+1

    // S = Q @ K^T : key = 2*l15 + cf
    f32x4 sv[2];
    __builtin_amdgcn_s_setprio(1);
    #pragma unroll
    for (int cf = 0; cf < 2; ++cf) {
      f32x4 a = (f32x4){0.f,0.f,0.f,0.f};
      const int r = 2 * l15 + cf;
      #pragma unroll
      for (int kk = 0; kk < 2; ++kk)
        a = MFMA16(aq[kk], ldsv8(&lKt[r * 64 + ((kk * 32 + l4 * 8) ^ ((l15 & 7) << 3))]), a);
      sv[cf] = a;
    }
    __builtin_amdgcn_s_setprio(0);

    // spike gate + mask + fixed-max softmax numerator
    float pvv[2][4];
    #pragma unroll
    for (int cf = 0; cf < 2; ++cf) {
      const float kth = cf ? klA.z : klA.x;
      const float klm = cf ? klA.w : klA.y;
      #pragma unroll
      for (int e = 0; e < 4; ++e) {
        float s = fminf(fmaxf(sv[cf][e], -6.f), 6.f);
        const float t = __builtin_amdgcn_exp2f(fmaf(s, C_NEG5L2E, kth));
        const float g = __builtin_amdgcn_rcpf(1.f + t);
        float md = fmaf(s + s, g, s);                       // s*(1+2g) in [-18,18]
        md = fminf(md, fminf(klm, limq[e]));                // mask -> -30
        const float p = __builtin_amdgcn_exp2f(fmaf(md, C_L2E, -C_18L2E)); // exp(md-18)
        pvv[cf][e] = p;
        lrun[e] += p;
      }
    }

    // P -> per-wave LDS: packed pair writes (keys 2l15, 2l15+1)
    #pragma unroll
    for (int e = 0; e < 4; ++e) {
      const int rr = l4 * 4 + e;
      union { unsigned short us[2]; unsigned int u; } pk2;
      pk2.us[0] = f2bf(pvv[0][e]);
      pk2.us[1] = f2bf(pvv[1][e]);
      *(unsigned int*)&lPw[rr * 32 + ((2 * l15) ^ ((rr & 3) << 3))] = pk2.u;
    }
    asm volatile("s_waitcnt lgkmcnt(0)" ::: "memory");
    __builtin_amdgcn_sched_barrier(0);

    const bf16x8 pa = ldsv8(&lPw[l15 * 32 + ((l4 * 8) ^ ((l15 & 3) << 3))]);

    __builtin_amdgcn_s_setprio(1);
    #pragma unroll
    for (int df = 0; df < 4; ++df) {
      const int d = df * 16 + l15;
      o[df] = MFMA16(pa, ldsv8(&lVt[d * 32 + ((l4 * 8) ^ ((d & 3) << 3))]), o[df]);
    }
    __builtin_amdgcn_s_setprio(0);

    if (pr < 31) {
      const int nxt = cur ^ 1;
      *(u32x4*)&lK[nxt * 4096 + kdst] = kr;
      *(u32x4*)&lV[nxt * 4096 + vdst] = vr;
    }
    __syncthreads();
  }

  // merge parity partials via LDS (smem reuse), normalize, store
  __syncthreads();
  float* xch = (float*)smem;
  float* slot = xch + rg * 1280;
  if (par) {
    #pragma unroll
    for (int df = 0; df < 4; ++df)
      *(f32x4*)&slot[(df * 64 + lane) * 4] = o[df];
    f32x4 lr;
    lr[0] = lrun[0]; lr[1] = lrun[1]; lr[2] = lrun[2]; lr[3] = lrun[3];
    *(f32x4*)&slot[1024 + lane * 4] = lr;
  }
  __syncthreads();
  if (!par) {
    #pragma unroll
    for (int df = 0; df < 4; ++df) {
      const f32x4 t = *(const f32x4*)&slot[(df * 64 + lane) * 4];
      o[df][0] += t[0]; o[df][1] += t[1]; o[df][2] += t[2]; o[df][3] += t[3];
    }
    const f32x4 lr = *(const f32x4*)&slot[1024 + lane * 4];
    #pragma unroll
    for (int e = 0; e < 4; ++e) {
      float ls = lrun[e] + lr[e];
      ls += __shfl_xor(ls, 1);
      ls += __shfl_xor(ls, 2);
      ls += __shfl_xor(ls, 4);
      ls += __shfl_xor(ls, 8);
      const float rl = __builtin_amdgcn_rcpf(ls);
      const int r = qr0 + l4 * 4 + e;
      #pragma unroll
      for (int df = 0; df < 4; ++df) {
        outg[(b * SS + r) * DM + h * HD + df * 16 + l15] = f2bf(o[df][e] * rl);
      }
    }
  }
}

// ---------------- launcher ----------------
extern "C" void kernel_launch(void* const* d_in, const int* in_sizes, int n_in,
                              void* d_out, int out_size, void* d_ws, size_t ws_size,
                              hipStream_t stream)
{
  const float* query   = (const float*)d_in[0];
  const float* key_in  = (const float*)d_in[1];
  const float* value   = (const float*)d_in[2];
  const int*   mask    = (const int*)d_in[3];
  const float* density = (const float*)d_in[4];
  const float* wq_r = (const float*)d_in[5];
  const float* wq_i = (const float*)d_in[6];
  const float* wq_j = (const float*)d_in[7];
  const float* wq_k = (const float*)d_in[8];
  const float* bq   = (const float*)d_in[9];
  const float* wk_r = (const float*)d_in[10];
  const float* wk_i = (const float*)d_in[11];
  const float* wk_j = (const float*)d_in[12];
  const float* wk_k = (const float*)d_in[13];
  const float* bk   = (const float*)d_in[14];
  const float* wv   = (const float*)d_in[15];
  const float* bv   = (const float*)d_in[16];
  const float* wo   = (const float*)d_in[17];
  const float* bo   = (const float*)d_in[18];
  const float* thrs = (const float*)d_in[19];
  const float* dm1w = (const float*)d_in[20];
  const float* dm1b = (const float*)d_in[21];
  const float* dm2w = (const float*)d_in[22];
  const float* dm2b = (const float*)d_in[23];

  char* ws = (char*)d_ws;
  unsigned short* Wq  = (unsigned short*)(ws + ((size_t)0 << 20));
  unsigned short* Wk  = (unsigned short*)(ws + ((size_t)2 << 20));
  unsigned short* Wv  = (unsigned short*)(ws + ((size_t)4 << 20));
  unsigned short* Wo  = (unsigned short*)(ws + ((size_t)6 << 20));
  unsigned short* qbf = (unsigned short*)(ws + ((size_t)8 << 20));
  unsigned short* kbf = (unsigned short*)(ws + ((size_t)16 << 20));
  unsigned short* vT  = (unsigned short*)(ws + ((size_t)24 << 20));
  unsigned short* att = (unsigned short*)(ws + ((size_t)32 << 20));
  float2* klim        = (float2*)(ws + ((size_t)40 << 20));

  unsigned short* qcv = (unsigned short*)d_out;
  unsigned short* kcv = (unsigned short*)d_out + (size_t)MTOT * DM;
  unsigned short* vcv = att;

  prep_all<<<2576, 256, 0, stream>>>(
      wq_r, wq_i, wq_j, wq_k, wk_r, wk_i, wk_j, wk_k, wv, wo,
      Wq, Wk, Wv, Wo,
      query, key_in, value, qcv, kcv, vcv,
      density, dm1w, dm1b, dm2w, dm2b, thrs, mask, klim);

  GemmArgs qkv;
  qkv.A[0] = qcv; qkv.W[0] = Wq; qkv.bias[0] = bq; qkv.out[0] = qbf; qkv.scale[0] = 0.25f; qkv.omode[0] = 0;
  qkv.A[1] = kcv; qkv.W[1] = Wk; qkv.bias[1] = bk; qkv.out[1] = kbf; qkv.scale[1] = 1.0f;  qkv.omode[1] = 0;
  qkv.A[2] = vcv; qkv.W[2] = Wv; qkv.bias[2] = bv; qkv.out[2] = vT;  qkv.scale[2] = 1.0f;  qkv.omode[2] = 1;
  gemm_bt<0><<<dim3(256, 3), 256, 0, stream>>>(qkv);

  attn_kernel<<<1024, 512, 0, stream>>>(qbf, kbf, vT, klim, mask, att);

  GemmArgs og;
  og.A[0] = att; og.W[0] = Wo; og.bias[0] = bo; og.out[0] = d_out; og.scale[0] = 1.0f; og.omode[0] = 2;
  og.A[1] = att; og.W[1] = Wo; og.bias[1] = bo; og.out[1] = d_out; og.scale[1] = 1.0f; og.omode[1] = 2;
  og.A[2] = att; og.W[2] = Wo; og.bias[2] = bo; og.out[2] = d_out; og.scale[2] = 1.0f; og.omode[2] = 2;
  gemm_bt<1><<<dim3(256, 1), 256, 0, stream>>>(og);
}